// Round 13
// baseline (98.231 us; speedup 1.0000x reference)
//
#include <hip/hip_runtime.h>
#include <hip/hip_bf16.h>

#define SEQ 81
#define DIM 64
#define NT  192          // 3 waves; wave w owns i-bands {w, 5-w} -> causal-balanced
#define NW  6
#define LDK 68           // sK row stride in shorts
#define LDV 100          // sVt row stride in shorts
#define LDP 100          // sP row stride in shorts

typedef short bf16x8 __attribute__((ext_vector_type(8)));
typedef short bf16x4 __attribute__((ext_vector_type(4)));
typedef float f32x4  __attribute__((ext_vector_type(4)));

static constexpr float kS2 = 0.0520587716f;   // log2(e) / sqrt(768) — folded scale

__device__ __forceinline__ short f2bf(float f) {
    __hip_bfloat16 h = __float2bfloat16(f);
    return __builtin_bit_cast(short, h);
}
__device__ __forceinline__ float bf2f(short h) {
    unsigned u = ((unsigned)(unsigned short)h) << 16;
    return __builtin_bit_cast(float, u);
}
__device__ __forceinline__ bf16x8 cat8(bf16x4 a, bf16x4 b) {
    bf16x8 r;
    r[0]=a[0]; r[1]=a[1]; r[2]=a[2]; r[3]=a[3];
    r[4]=b[0]; r[5]=b[1]; r[6]=b[2]; r[7]=b[3];
    return r;
}

__global__ void emb_cvt_kernel(const float* __restrict__ in, short* __restrict__ out, int n) {
    int i = blockIdx.x * 256 + threadIdx.x;
    if (i < n) out[i] = f2bf(i < n ? in[i] : 0.f);
}

// R10 structure (2 barriers, sP overlays sK, 5 blocks/CU, no setprio) with
// causal-BALANCED waves: 3 waves, wave w owns bands {w, 5-w} so every wave does
// identical causal work (7 QK + 7 Qe tiles, 16 PV MFMAs) -> no barrier convoy,
// no single-wave tail holding the block's LDS slot.
__global__ __launch_bounds__(NT, 4)
void rpsa_kernel(const float* __restrict__ Q, const float* __restrict__ K,
                 const float* __restrict__ V, const short* __restrict__ embw,
                 const int* __restrict__ ucp, float* __restrict__ out)
{
    extern __shared__ char smraw[];
    short* sVt = (short*)smraw;              // [64][100]  12800 B (V^T, bf16)
    short* sK  = (short*)(smraw + 12800);    // [96][68]   13056 B (bf16)
    short* sP  = (short*)(smraw + 12800);    // [96][100]  19200 B bias/P, overlays sK
    // total 32000 B -> 5 blocks/CU

    const int tid = threadIdx.x;
    const size_t base = (size_t)blockIdx.x * (SEQ * DIM);
    const int uc = ucp[0];
    const int w  = tid >> 6, L = tid & 63;
    const int lr = L & 15,  lg = L >> 4;
    const int bnd[2] = { w, 5 - w };         // this wave's two i-bands
    int iR[2];
    iR[0] = 16*bnd[0] + lr;
    iR[1] = 16*bnd[1] + lr;

    // ---- Q B-fragments for both bands, pre-scaled by log2e/sqrt(768) ----
    bf16x8 aq[2][2];
    #pragma unroll
    for (int b = 0; b < 2; ++b) {
        const int qrow = (iR[b] < SEQ) ? iR[b] : (SEQ - 1);   // clamp pad lanes
        const float* qp = Q + base + qrow*DIM + 8*lg;
        const f32x4 q0 = *(const f32x4*)(qp);
        const f32x4 q1 = *(const f32x4*)(qp + 4);
        const f32x4 q2 = *(const f32x4*)(qp + 32);
        const f32x4 q3 = *(const f32x4*)(qp + 36);
        #pragma unroll
        for (int t = 0; t < 4; ++t) {
            aq[b][0][t]   = f2bf(q0[t]*kS2);
            aq[b][0][4+t] = f2bf(q1[t]*kS2);
            aq[b][1][t]   = f2bf(q2[t]*kS2);
            aq[b][1][4+t] = f2bf(q3[t]*kS2);
        }
    }

    // ---- stage K bf16 (rows >= 81 zeroed); 4 iters ----
    for (int u = tid; u < 96 * DIM / 8; u += NT) {
        const int row = u >> 3, so = (u & 7) * 8;
        bf16x4 lo = {0,0,0,0}, hi = {0,0,0,0};
        if (row < SEQ) {
            const f32x4 k0 = *(const f32x4*)(K + base + row*DIM + so);
            const f32x4 k1 = *(const f32x4*)(K + base + row*DIM + so + 4);
            #pragma unroll
            for (int t = 0; t < 4; ++t) { lo[t] = f2bf(k0[t]); hi[t] = f2bf(k1[t]); }
        }
        *(bf16x4*)(sK + row*LDK + so)     = lo;
        *(bf16x4*)(sK + row*LDK + so + 4) = hi;
    }
    // ---- stage V transposed (4x4 register transpose); 2 iters ----
    for (int u = tid; u < 384; u += NT) {
        const int j4 = u >> 4;            // 0..23
        const int d4 = u & 15;            // 0..15
        f32x4 rw[4];
        #pragma unroll
        for (int e = 0; e < 4; ++e) {
            const int j = 4*j4 + e;
            rw[e] = (j < SEQ) ? *(const f32x4*)(V + base + j*DIM + 4*d4)
                              : (f32x4){0.f,0.f,0.f,0.f};
        }
        #pragma unroll
        for (int c = 0; c < 4; ++c) {
            const int d = 4*d4 + c;
            bf16x4 pv = { f2bf(rw[0][c]), f2bf(rw[1][c]), f2bf(rw[2][c]), f2bf(rw[3][c]) };
            *(bf16x4*)(sVt + d*LDV + 4*j4) = pv;
        }
    }

    // ---- Qe pass-1 prefetch, both bands (embw bf16, L1-resident) ----
    // lane gets Qe[iR[b]][rel = 80 + 16nt2 + 4lg + r]; scatter deferred to post-bar2.
    bf16x4 qe[2][NW];
    #pragma unroll
    for (int b = 0; b < 2; ++b) {
        #pragma unroll
        for (int nt2 = 0; nt2 < NW; ++nt2) {
            if (nt2 > bnd[b]) continue;
            int erow = 80 + 16*nt2 + lr;
            if (erow > 2*SEQ) erow = 2*SEQ;      // clamp: corrupts only pad-row writes
            bf16x8 e0 = *(const bf16x8*)(embw + erow*DIM + 8*lg);
            bf16x8 e1 = *(const bf16x8*)(embw + erow*DIM + 32 + 8*lg);
            f32x4 a = {0.f,0.f,0.f,0.f};
            a = __builtin_amdgcn_mfma_f32_16x16x32_bf16(e0, aq[b][0], a, 0, 0, 0);
            a = __builtin_amdgcn_mfma_f32_16x16x32_bf16(e1, aq[b][1], a, 0, 0, 0);
            bf16x4 p = { f2bf(a[0]), f2bf(a[1]), f2bf(a[2]), f2bf(a[3]) };
            qe[b][nt2] = p;
        }
    }
    __syncthreads();   // bar1: sK/sVt staged

    // ---- QK^T from sK, both bands: accs[b][nt][r] = S[iR[b]][16nt+4lg+r] ----
    f32x4 accs[2][NW] = {};
    int ntEnd[2];
    ntEnd[0] = uc ? bnd[0] : (NW - 1);
    ntEnd[1] = uc ? bnd[1] : (NW - 1);
    #pragma unroll
    for (int b = 0; b < 2; ++b) {
        #pragma unroll
        for (int nt = 0; nt < NW; ++nt) {
            if (nt > ntEnd[b]) continue;
            const int kr = 16*nt + lr;
            bf16x8 b0 = cat8(*(const bf16x4*)(sK + kr*LDK + 8*lg),
                             *(const bf16x4*)(sK + kr*LDK + 8*lg + 4));
            bf16x8 b1 = cat8(*(const bf16x4*)(sK + kr*LDK + 32 + 8*lg),
                             *(const bf16x4*)(sK + kr*LDK + 32 + 8*lg + 4));
            f32x4 a = accs[b][nt];
            a = __builtin_amdgcn_mfma_f32_16x16x32_bf16(b0, aq[b][0], a, 0, 0, 0);
            a = __builtin_amdgcn_mfma_f32_16x16x32_bf16(b1, aq[b][1], a, 0, 0, 0);
            accs[b][nt] = a;
        }
    }
    __syncthreads();   // bar2: sK dead -> sP overlay live

    // ---- scatter prefetched pass-1 bias into sP (own rows -> race-free) ----
    #pragma unroll
    for (int b = 0; b < 2; ++b) {
        #pragma unroll
        for (int nt2 = 0; nt2 < NW; ++nt2) {
            if (nt2 > bnd[b]) continue;
            #pragma unroll
            for (int r = 0; r < 4; ++r) {
                const int j = iR[b] - 16*nt2 - 4*lg - r;   // j = i - (rel-80)
                if (j >= 0) sP[iR[b]*LDP + j] = qe[b][nt2][r];
            }
        }
    }
    // ---- pass-0 (non-causal only): rel in [i,79], j = 80+i-rel > i ----
    if (!uc) {
        #pragma unroll
        for (int b = 0; b < 2; ++b) {
            #pragma unroll
            for (int nt2 = 0; nt2 < NW - 1; ++nt2) {
                if (nt2 < bnd[b]) continue;
                const int erow = 16*nt2 + lr;    // <= 79
                bf16x8 e0 = *(const bf16x8*)(embw + erow*DIM + 8*lg);
                bf16x8 e1 = *(const bf16x8*)(embw + erow*DIM + 32 + 8*lg);
                f32x4 a = {0.f,0.f,0.f,0.f};
                a = __builtin_amdgcn_mfma_f32_16x16x32_bf16(e0, aq[b][0], a, 0, 0, 0);
                a = __builtin_amdgcn_mfma_f32_16x16x32_bf16(e1, aq[b][1], a, 0, 0, 0);
                #pragma unroll
                for (int r = 0; r < 4; ++r) {
                    const int rel = 16*nt2 + 4*lg + r;
                    if (rel >= iR[b]) sP[iR[b]*LDP + (80 + iR[b] - rel)] = f2bf(a[r]);
                }
            }
        }
    }
    // No barrier: each wave's bias slots are produced and consumed by the same wave.

    // ---- fused softmax, both bands (no max-subtraction; scores bounded) ----
    float inv[2];
    #pragma unroll
    for (int b = 0; b < 2; ++b) {
        const int jmax = uc ? ((iR[b] < SEQ-1) ? iR[b] : SEQ-1) : (SEQ-1);
        float sum = 0.f;
        #pragma unroll
        for (int nt = 0; nt < NW; ++nt) {
            short* slot = sP + iR[b]*LDP + 16*nt + 4*lg;
            if (nt <= ntEnd[b]) {
                bf16x4 bias = *(const bf16x4*)(slot);
                bf16x4 p;
                #pragma unroll
                for (int r = 0; r < 4; ++r) {
                    const int j = 16*nt + 4*lg + r;
                    const float x = accs[b][nt][r] + bf2f(bias[r]);
                    const float e = (j <= jmax) ? exp2f(x) : 0.f;
                    sum += e;
                    p[r] = f2bf(e);
                }
                *(bf16x4*)(slot) = p;
            } else {
                *(bf16x4*)(slot) = (bf16x4){0,0,0,0};   // dead causal tiles -> P = 0
            }
        }
        sum += __shfl_xor(sum, 16);
        sum += __shfl_xor(sum, 32);
        inv[b] = 1.f / sum;
    }

    // ---- PV, both bands: lane gets O[iR[b]][d = 16nt + 4lg + r]; causal trim ----
    #pragma unroll
    for (int b = 0; b < 2; ++b) {
        const int nks = uc ? ((bnd[b] >> 1) + 1) : 3;   // P == 0 beyond j = 16*bnd+15
        bf16x8 ap0, ap1, ap2;
        ap0 = cat8(*(const bf16x4*)(sP + iR[b]*LDP + 8*lg),
                   *(const bf16x4*)(sP + iR[b]*LDP + 8*lg + 4));
        if (nks > 1)
            ap1 = cat8(*(const bf16x4*)(sP + iR[b]*LDP + 32 + 8*lg),
                       *(const bf16x4*)(sP + iR[b]*LDP + 32 + 8*lg + 4));
        if (nks > 2)
            ap2 = cat8(*(const bf16x4*)(sP + iR[b]*LDP + 64 + 8*lg),
                       *(const bf16x4*)(sP + iR[b]*LDP + 64 + 8*lg + 4));
        #pragma unroll
        for (int nt = 0; nt < 4; ++nt) {
            const int d = 16*nt + lr;
            f32x4 a = {0.f,0.f,0.f,0.f};
            bf16x8 b0 = cat8(*(const bf16x4*)(sVt + d*LDV + 8*lg),
                             *(const bf16x4*)(sVt + d*LDV + 8*lg + 4));
            a = __builtin_amdgcn_mfma_f32_16x16x32_bf16(b0, ap0, a, 0, 0, 0);
            if (nks > 1) {
                bf16x8 b1 = cat8(*(const bf16x4*)(sVt + d*LDV + 32 + 8*lg),
                                 *(const bf16x4*)(sVt + d*LDV + 32 + 8*lg + 4));
                a = __builtin_amdgcn_mfma_f32_16x16x32_bf16(b1, ap1, a, 0, 0, 0);
            }
            if (nks > 2) {
                bf16x8 b2 = cat8(*(const bf16x4*)(sVt + d*LDV + 64 + 8*lg),
                                 *(const bf16x4*)(sVt + d*LDV + 64 + 8*lg + 4));
                a = __builtin_amdgcn_mfma_f32_16x16x32_bf16(b2, ap2, a, 0, 0, 0);
            }
            if (iR[b] < SEQ) {
                f32x4 o = { a[0]*inv[b], a[1]*inv[b], a[2]*inv[b], a[3]*inv[b] };
                *(f32x4*)(out + base + iR[b]*DIM + 16*nt + 4*lg) = o;
            }
        }
    }
}

extern "C" void kernel_launch(void* const* d_in, const int* in_sizes, int n_in,
                              void* d_out, int out_size, void* d_ws, size_t ws_size,
                              hipStream_t stream) {
    const float* Q   = (const float*)d_in[0];
    const float* K   = (const float*)d_in[1];
    const float* V   = (const float*)d_in[2];
    const float* emb = (const float*)d_in[3];
    const int*   uc  = (const int*)d_in[4];
    float* out = (float*)d_out;

    const int nbh   = in_sizes[0] / (SEQ * DIM);   // 4096
    const int n_emb = in_sizes[3];                 // 163*64

    short* embw = (short*)d_ws;
    emb_cvt_kernel<<<(n_emb + 255) / 256, 256, 0, stream>>>(emb, embw, n_emb);

    const size_t smem = 32000;   // sVt 12800 + max(sK 13056, sP 19200)
    hipFuncSetAttribute(reinterpret_cast<const void*>(rpsa_kernel),
                        hipFuncAttributeMaxDynamicSharedMemorySize, (int)smem);
    rpsa_kernel<<<nbh, NT, smem, stream>>>(Q, K, V, embw, uc, out);
}